// Round 2
// baseline (1938.278 us; speedup 1.0000x reference)
//
#include <hip/hip_runtime.h>

typedef __attribute__((ext_vector_type(8))) short short8;
typedef __attribute__((ext_vector_type(4))) float floatx4;

__device__ __forceinline__ float b2f(unsigned short u) {
  union { unsigned int i; float f; } c; c.i = ((unsigned int)u) << 16; return c.f;
}
__device__ __forceinline__ unsigned short f2b(float f) {
  union { float f; unsigned int i; } c; c.f = f;
  unsigned int i = c.i;
  return (unsigned short)((i + 0x7FFFu + ((i >> 16) & 1u)) >> 16);
}
__device__ __forceinline__ float elu_f(float x) {
  return x > 0.f ? x : (expf(x) - 1.f);
}
__device__ __forceinline__ float silu_f(float x) {
  return x / (1.f + expf(-x));
}

// ---------------- dtype detector ----------------
// If x is packed bf16, the low 16 bits of each 32b word are a bf16 of a ~N(0,1)
// value -> exponent field near 127. If x is fp32, low 16 bits are random
// mantissa bits -> exponent field uniform. Count sane-exponent words.
__global__ __launch_bounds__(256) void detect_dtype(
    const unsigned int* __restrict__ x, int* __restrict__ cnt) {
  int t = threadIdx.x;
  int c = 0;
  for (int i = t; i < 4096; i += 256) {
    unsigned int lo = x[i] & 0xFFFFu;
    unsigned int e = (lo >> 7) & 0xFFu;
    if (e >= 0x70u && e <= 0x8Fu) c++;
  }
#pragma unroll
  for (int off = 32; off > 0; off >>= 1) c += __shfl_down(c, off, 64);
  if ((t & 63) == 0) atomicAdd(cnt, c);
}
__device__ __forceinline__ bool is_f32(const int* flag) { return flag[0] < 2048; }

// ---------------- weight transpose (2048x2048) -> bf16 ----------------
__global__ __launch_bounds__(256) void transpose2048(
    const void* __restrict__ src, unsigned short* __restrict__ dst,
    const int* __restrict__ flag) {
  const bool f32 = is_f32(flag);
  __shared__ unsigned short tile[32][33];
  int bx = blockIdx.x * 32;  // src col
  int by = blockIdx.y * 32;  // src row
  int tx = threadIdx.x & 31;
  int ty = threadIdx.x >> 5;  // 0..7
  for (int i = ty; i < 32; i += 8) {
    size_t idx = (size_t)(by + i) * 2048 + bx + tx;
    tile[i][tx] = f32 ? f2b(((const float*)src)[idx]) : ((const unsigned short*)src)[idx];
  }
  __syncthreads();
  for (int i = ty; i < 32; i += 8)
    dst[(size_t)(bx + i) * 2048 + by + tx] = tile[tx][i];
}

// ---------------- GEMM: C = act(A @ W + bias), W transposed bf16 ----------------
// A: M x K row-major (bf16 internal, or external: bf16/fp32 per flag)
// WT: Nc x K row-major bf16, C: M x Nc (internal bf16 or external per flag)
// grid: (Nc/128, M/128), block 256. act: 0=none, 1=silu
__global__ __launch_bounds__(256) void gemm_bias_act(
    const void* __restrict__ A, int a_ext,
    const unsigned short* __restrict__ WT,
    const void* __restrict__ bias,
    void* __restrict__ C, int c_ext,
    int K, int Nc, int act, const int* __restrict__ flag) {
  const bool f32 = is_f32(flag);
  const bool a32 = a_ext && f32;
  __shared__ __align__(16) unsigned short As[128][72];
  __shared__ __align__(16) unsigned short Bs[128][72];
  const int bn = blockIdx.x * 128;
  const int bm = blockIdx.y * 128;
  const int t = threadIdx.x;
  const int lane = t & 63;
  const int wave = t >> 6;
  const int lm = lane & 15;
  const int quad = lane >> 4;
  const int wm = (wave >> 1) * 64;
  const int wn = (wave & 1) * 64;
  floatx4 acc[4][4] = {};

  const int r0 = t >> 3;  // 0..31
  const int g0 = t & 7;   // 8-elem group within 64-col k-tile
  for (int kt = 0; kt < K; kt += 64) {
#pragma unroll
    for (int i = 0; i < 4; ++i) {
      int r = r0 + 32 * i;
      if (a32) {
        const float* Af = (const float*)A + (size_t)(bm + r) * K + kt + g0 * 8;
        float4 u0 = *(const float4*)Af;
        float4 u1 = *(const float4*)(Af + 4);
        unsigned short p[8] = {f2b(u0.x), f2b(u0.y), f2b(u0.z), f2b(u0.w),
                               f2b(u1.x), f2b(u1.y), f2b(u1.z), f2b(u1.w)};
        *(uint4*)&As[r][g0 * 8] = *(uint4*)p;
      } else {
        *(uint4*)&As[r][g0 * 8] =
            *(const uint4*)((const unsigned short*)A + (size_t)(bm + r) * K + kt + g0 * 8);
      }
      *(uint4*)&Bs[r][g0 * 8] =
          *(const uint4*)(WT + (size_t)(bn + r) * K + kt + g0 * 8);
    }
    __syncthreads();
#pragma unroll
    for (int ks = 0; ks < 2; ++ks) {
      short8 af[4], bf[4];
#pragma unroll
      for (int mi = 0; mi < 4; ++mi)
        af[mi] = *(const short8*)&As[wm + mi * 16 + lm][ks * 32 + quad * 8];
#pragma unroll
      for (int ni = 0; ni < 4; ++ni)
        bf[ni] = *(const short8*)&Bs[wn + ni * 16 + lm][ks * 32 + quad * 8];
#pragma unroll
      for (int mi = 0; mi < 4; ++mi)
#pragma unroll
        for (int ni = 0; ni < 4; ++ni)
          acc[mi][ni] = __builtin_amdgcn_mfma_f32_16x16x32_bf16(
              af[mi], bf[ni], acc[mi][ni], 0, 0, 0);
    }
    __syncthreads();
  }
#pragma unroll
  for (int ni = 0; ni < 4; ++ni) {
    int col = bn + wn + ni * 16 + lm;
    float bv = f32 ? ((const float*)bias)[col] : b2f(((const unsigned short*)bias)[col]);
#pragma unroll
    for (int mi = 0; mi < 4; ++mi) {
#pragma unroll
      for (int r = 0; r < 4; ++r) {
        int row = bm + wm + mi * 16 + quad * 4 + r;
        float v = acc[mi][ni][r] + bv;
        if (act == 1) v = silu_f(v);
        size_t idx = (size_t)row * Nc + col;
        if (c_ext && f32) ((float*)C)[idx] = v;
        else ((unsigned short*)C)[idx] = f2b(v);
      }
    }
  }
}

// ---------------- kv accumulation: kvT[b,h][e][d] += sum_n elu(K)[n,d] * V[n,e] ----------------
// grid: (64, 8), block 256; chunk = 512 tokens per split, atomicAdd into fp32 kvT
__global__ __launch_bounds__(256) void kv_accum(
    const unsigned short* __restrict__ QK,
    const unsigned short* __restrict__ V,
    float* __restrict__ kvT, int chunk) {
  const int bh = blockIdx.x;  // b*16+h
  const int sp = blockIdx.y;
  const int b = bh >> 4, h = bh & 15;
  __shared__ __align__(16) unsigned short Kt[128][72];  // [d][n]
  __shared__ __align__(16) unsigned short Vt[128][72];  // [e][n]
  const int t = threadIdx.x;
  const int lane = t & 63, wave = t >> 6;
  const int lm = lane & 15, quad = lane >> 4;
  const int wm = (wave >> 1) * 64, wn = (wave & 1) * 64;
  floatx4 acc[4][4] = {};
  const size_t base = (size_t)b * 4096 * 2048 + (size_t)h * 128;
  const int nl = t & 63;   // n within 64-chunk
  const int dg0 = t >> 6;  // 0..3
  for (int n0 = sp * chunk; n0 < (sp + 1) * chunk; n0 += 64) {
#pragma unroll
    for (int i = 0; i < 4; ++i) {
      int dg = dg0 + 4 * i;  // 0..15
      union { uint4 u; unsigned short s[8]; } vk, vv;
      vk.u = *(const uint4*)(QK + base + (size_t)(n0 + nl) * 2048 + dg * 8);
      vv.u = *(const uint4*)(V + base + (size_t)(n0 + nl) * 2048 + dg * 8);
#pragma unroll
      for (int j = 0; j < 8; ++j) {
        Kt[dg * 8 + j][nl] = f2b(elu_f(b2f(vk.s[j])));
        Vt[dg * 8 + j][nl] = vv.s[j];
      }
    }
    __syncthreads();
#pragma unroll
    for (int ks = 0; ks < 2; ++ks) {
      short8 af[4], bf[4];
#pragma unroll
      for (int mi = 0; mi < 4; ++mi)
        af[mi] = *(const short8*)&Kt[wm + mi * 16 + lm][ks * 32 + quad * 8];
#pragma unroll
      for (int ni = 0; ni < 4; ++ni)
        bf[ni] = *(const short8*)&Vt[wn + ni * 16 + lm][ks * 32 + quad * 8];
#pragma unroll
      for (int mi = 0; mi < 4; ++mi)
#pragma unroll
        for (int ni = 0; ni < 4; ++ni)
          acc[mi][ni] = __builtin_amdgcn_mfma_f32_16x16x32_bf16(
              af[mi], bf[ni], acc[mi][ni], 0, 0, 0);
    }
    __syncthreads();
  }
  float* dst = kvT + (size_t)bh * 128 * 128;
#pragma unroll
  for (int mi = 0; mi < 4; ++mi)
#pragma unroll
    for (int ni = 0; ni < 4; ++ni)
#pragma unroll
      for (int r = 0; r < 4; ++r) {
        int d = wm + mi * 16 + quad * 4 + r;
        int e = wn + ni * 16 + lm;
        atomicAdd(&dst[e * 128 + d], acc[mi][ni][r]);
      }
}

// ---------------- attention out: O[n, h*128+e] = sum_d elu(Q)[n,d] * kv[d,e] (bf16 out) ----------------
// grid: (16 heads, M/128), block 256
__global__ __launch_bounds__(256) void attn_out(
    const unsigned short* __restrict__ QK,
    const float* __restrict__ kvT,
    unsigned short* __restrict__ O) {
  const int h = blockIdx.x;
  const int bm = blockIdx.y * 128;
  const int b = bm >> 12;
  const int bh = b * 16 + h;
  __shared__ __align__(16) unsigned short As[128][136];  // [n-row][d]
  __shared__ __align__(16) unsigned short Bs[128][136];  // [e][d]
  const int t = threadIdx.x;
  const int lane = t & 63, wave = t >> 6;
  const int lm = lane & 15, quad = lane >> 4;
  const int wm = (wave >> 1) * 64, wn = (wave & 1) * 64;
  {
    const int r0 = t >> 4;  // 0..15
    const int g = t & 15;
#pragma unroll
    for (int i = 0; i < 8; ++i) {
      int r = r0 + 16 * i;
      union { uint4 u; unsigned short s[8]; } vq, w;
      vq.u = *(const uint4*)(QK + (size_t)(bm + r) * 2048 + h * 128 + g * 8);
#pragma unroll
      for (int j = 0; j < 8; ++j) w.s[j] = f2b(elu_f(b2f(vq.s[j])));
      *(uint4*)&As[r][g * 8] = w.u;
    }
    const int e0 = t >> 5;  // 0..7
    const int gg = t & 31;
    const float* kvp = kvT + (size_t)bh * 16384;
#pragma unroll
    for (int i = 0; i < 16; ++i) {
      int e = e0 + 8 * i;
      float4 f = *(const float4*)(kvp + e * 128 + gg * 4);
      unsigned short o4[4] = {f2b(f.x), f2b(f.y), f2b(f.z), f2b(f.w)};
      *(uint2*)&Bs[e][gg * 4] = *(uint2*)o4;
    }
  }
  __syncthreads();
  floatx4 acc[4][4] = {};
#pragma unroll
  for (int ks = 0; ks < 4; ++ks) {
    short8 af[4], bf[4];
#pragma unroll
    for (int mi = 0; mi < 4; ++mi)
      af[mi] = *(const short8*)&As[wm + mi * 16 + lm][ks * 32 + quad * 8];
#pragma unroll
    for (int ni = 0; ni < 4; ++ni)
      bf[ni] = *(const short8*)&Bs[wn + ni * 16 + lm][ks * 32 + quad * 8];
#pragma unroll
    for (int mi = 0; mi < 4; ++mi)
#pragma unroll
      for (int ni = 0; ni < 4; ++ni)
        acc[mi][ni] = __builtin_amdgcn_mfma_f32_16x16x32_bf16(
            af[mi], bf[ni], acc[mi][ni], 0, 0, 0);
  }
#pragma unroll
  for (int mi = 0; mi < 4; ++mi)
#pragma unroll
    for (int ni = 0; ni < 4; ++ni)
#pragma unroll
      for (int r = 0; r < 4; ++r) {
        int row = bm + wm + mi * 16 + quad * 4 + r;
        int e = wn + ni * 16 + lm;
        O[(size_t)row * 2048 + h * 128 + e] = f2b(acc[mi][ni][r]);
      }
}

// ---------------- layernorm(O) * U -> T (in-place over O; block = one row) ----------------
__global__ __launch_bounds__(256) void ln_mul(
    const unsigned short* __restrict__ O,
    const unsigned short* __restrict__ U,
    const void* __restrict__ g,
    const void* __restrict__ bb,
    unsigned short* __restrict__ T, const int* __restrict__ flag) {
  const bool f32 = is_f32(flag);
  const int row = blockIdx.x;
  const int t = threadIdx.x;
  const unsigned short* o = O + (size_t)row * 2048;
  float vals[8];
  float s = 0.f, s2 = 0.f;
#pragma unroll
  for (int i = 0; i < 8; ++i) {
    float f = b2f(o[t + 256 * i]);
    vals[i] = f;
    s += f;
    s2 += f * f;
  }
#pragma unroll
  for (int off = 32; off > 0; off >>= 1) {
    s += __shfl_down(s, off, 64);
    s2 += __shfl_down(s2, off, 64);
  }
  __shared__ float ps[4], ps2[4];
  int lane = t & 63, wave = t >> 6;
  if (lane == 0) { ps[wave] = s; ps2[wave] = s2; }
  __syncthreads();
  float S = ps[0] + ps[1] + ps[2] + ps[3];
  float S2 = ps2[0] + ps2[1] + ps2[2] + ps2[3];
  float mu = S * (1.f / 2048.f);
  float var = S2 * (1.f / 2048.f) - mu * mu;
  float rs = rsqrtf(var + 1e-5f);
#pragma unroll
  for (int i = 0; i < 8; ++i) {
    int c = t + 256 * i;
    float gv = f32 ? ((const float*)g)[c] : b2f(((const unsigned short*)g)[c]);
    float bv = f32 ? ((const float*)bb)[c] : b2f(((const unsigned short*)bb)[c]);
    float nv = (vals[i] - mu) * rs * gv + bv;
    float uu = b2f(U[(size_t)row * 2048 + c]);
    T[(size_t)row * 2048 + c] = f2b(nv * uu);
  }
}

extern "C" void kernel_launch(void* const* d_in, const int* in_sizes, int n_in,
                              void* d_out, int out_size, void* d_ws, size_t ws_size,
                              hipStream_t stream) {
  const void* x   = d_in[0];
  const void* Wqk = d_in[1];
  const void* bqk = d_in[2];
  const void* Wv  = d_in[3];
  const void* bv  = d_in[4];
  const void* Wu  = d_in[5];
  const void* bu  = d_in[6];
  const void* Wo  = d_in[7];
  const void* bo  = d_in[8];
  const void* lng = d_in[9];
  const void* lnb = d_in[10];

  char* ws = (char*)d_ws;
  const size_t MB = 1024 * 1024;
  int* flag = (int*)ws;                                   // [0, 4K)
  unsigned short* WT   = (unsigned short*)(ws + 1 * MB);  // 8 MiB (reused 4x)
  unsigned short* buf0 = (unsigned short*)(ws + 16 * MB); // 64 MiB: QK -> U
  unsigned short* buf1 = (unsigned short*)(ws + 80 * MB); // 64 MiB: V -> O -> T
  float* kvT = (float*)(ws + 144 * MB);                   // 4 MiB
  // total 148 MiB

  dim3 tb(256);
  hipMemsetAsync(flag, 0, 4096, stream);
  hipMemsetAsync(kvT, 0, (size_t)64 * 128 * 128 * 4, stream);
  detect_dtype<<<1, tb, 0, stream>>>((const unsigned int*)x, flag);

  // QK = x @ Wqk + bqk
  transpose2048<<<dim3(64, 64), tb, 0, stream>>>(Wqk, WT, flag);
  gemm_bias_act<<<dim3(16, 128), tb, 0, stream>>>(x, 1, WT, bqk, buf0, 0, 2048, 2048, 0, flag);
  // V = silu(x @ Wv + bv)
  transpose2048<<<dim3(64, 64), tb, 0, stream>>>(Wv, WT, flag);
  gemm_bias_act<<<dim3(16, 128), tb, 0, stream>>>(x, 1, WT, bv, buf1, 0, 2048, 2048, 1, flag);
  // kv = elu(K)^T V
  kv_accum<<<dim3(64, 8), tb, 0, stream>>>(buf0, buf1, kvT, 512);
  // O = elu(Q) @ kv   (overwrites V buffer)
  attn_out<<<dim3(16, 128), tb, 0, stream>>>(buf0, kvT, buf1);
  // U = silu(x @ Wu + bu)  (overwrites QK buffer)
  transpose2048<<<dim3(64, 64), tb, 0, stream>>>(Wu, WT, flag);
  gemm_bias_act<<<dim3(16, 128), tb, 0, stream>>>(x, 1, WT, bu, buf0, 0, 2048, 2048, 1, flag);
  // T = layernorm(O) * U  (in-place over O)
  ln_mul<<<16384, tb, 0, stream>>>(buf1, buf0, lng, lnb, buf1, flag);
  // out = T @ Wo + bo
  transpose2048<<<dim3(64, 64), tb, 0, stream>>>(Wo, WT, flag);
  gemm_bias_act<<<dim3(16, 128), tb, 0, stream>>>(buf1, 0, WT, bo, d_out, 1, 2048, 2048, 0, flag);
}

// Round 3
// 1347.717 us; speedup vs baseline: 1.4382x; 1.4382x over previous
//
#include <hip/hip_runtime.h>

typedef __attribute__((ext_vector_type(8))) short short8;
typedef __attribute__((ext_vector_type(4))) float floatx4;

__device__ __forceinline__ float b2f(unsigned short u) {
  union { unsigned int i; float f; } c; c.i = ((unsigned int)u) << 16; return c.f;
}
__device__ __forceinline__ unsigned short f2b(float f) {
  union { float f; unsigned int i; } c; c.f = f;
  unsigned int i = c.i;
  return (unsigned short)((i + 0x7FFFu + ((i >> 16) & 1u)) >> 16);
}
__device__ __forceinline__ float elu_f(float x) {
  return x > 0.f ? x : (expf(x) - 1.f);
}
__device__ __forceinline__ float silu_f(float x) {
  return x / (1.f + expf(-x));
}
__device__ __forceinline__ void async16(const unsigned short* g, unsigned short* l) {
  __builtin_amdgcn_global_load_lds(
      (const __attribute__((address_space(1))) void*)g,
      (__attribute__((address_space(3))) void*)l, 16, 0, 0);
}

// ---------------- dtype detector ----------------
__global__ __launch_bounds__(256) void detect_dtype(
    const unsigned int* __restrict__ x, int* __restrict__ cnt) {
  int t = threadIdx.x;
  int c = 0;
  for (int i = t; i < 4096; i += 256) {
    unsigned int lo = x[i] & 0xFFFFu;
    unsigned int e = (lo >> 7) & 0xFFu;
    if (e >= 0x70u && e <= 0x8Fu) c++;
  }
#pragma unroll
  for (int off = 32; off > 0; off >>= 1) c += __shfl_down(c, off, 64);
  if ((t & 63) == 0) atomicAdd(cnt, c);
}
__device__ __forceinline__ bool is_f32(const int* flag) { return flag[0] < 2048; }

// ---------------- x -> bf16 normalize (only writes on f32 path) ----------------
// grid 16384 x 256, 8 elems/thread over 33.5M elements
__global__ __launch_bounds__(256) void convert_x(
    const void* __restrict__ x, unsigned short* __restrict__ xb,
    const int* __restrict__ flag) {
  if (!is_f32(flag)) return;
  size_t i = ((size_t)blockIdx.x * 256 + threadIdx.x) * 8;
  const float* xf = (const float*)x;
  float4 a = *(const float4*)(xf + i);
  float4 b = *(const float4*)(xf + i + 4);
  unsigned short p[8] = {f2b(a.x), f2b(a.y), f2b(a.z), f2b(a.w),
                         f2b(b.x), f2b(b.y), f2b(b.z), f2b(b.w)};
  *(uint4*)(xb + i) = *(uint4*)p;
}

// ---------------- weight transpose (2048x2048) -> bf16 ----------------
__global__ __launch_bounds__(256) void transpose2048(
    const void* __restrict__ src, unsigned short* __restrict__ dst,
    const int* __restrict__ flag) {
  const bool f32 = is_f32(flag);
  __shared__ unsigned short tile[32][33];
  int bx = blockIdx.x * 32;
  int by = blockIdx.y * 32;
  int tx = threadIdx.x & 31;
  int ty = threadIdx.x >> 5;
  for (int i = ty; i < 32; i += 8) {
    size_t idx = (size_t)(by + i) * 2048 + bx + tx;
    tile[i][tx] = f32 ? f2b(((const float*)src)[idx]) : ((const unsigned short*)src)[idx];
  }
  __syncthreads();
  for (int i = ty; i < 32; i += 8)
    dst[(size_t)(bx + i) * 2048 + by + tx] = tile[tx][i];
}

// ---------------- GEMM (m97 structure): C = act(A @ W + bias) ----------------
// A0/A1: M x K bf16 (A1 used when a_sel && f32); WT: Nc x K bf16
// grid: (Nc/128, M/128), block 256
__global__ __launch_bounds__(256) void gemm_bias_act(
    const unsigned short* __restrict__ A0,
    const unsigned short* __restrict__ A1, int a_sel,
    const unsigned short* __restrict__ WT,
    const void* __restrict__ bias,
    void* __restrict__ C, int c_ext,
    int K, int Nc, int act, const int* __restrict__ flag) {
  const bool f32 = is_f32(flag);
  const unsigned short* A = (a_sel && f32) ? A1 : A0;
  __shared__ __align__(16) unsigned short As[128 * 64];
  __shared__ __align__(16) unsigned short Bs[128 * 64];
  const int bn = blockIdx.x * 128;
  const int bm = blockIdx.y * 128;
  const int t = threadIdx.x;
  const int lane = t & 63;
  const int wave = t >> 6;
  const int lm = lane & 15;
  const int quad = lane >> 4;
  const int wm = (wave >> 1) * 64;
  const int wn = (wave & 1) * 64;
  const int w32 = wave * 32;
  const int srow = lane >> 3;        // 0..7
  const int scol = (lane & 7) * 8;   // 8-short groups
  floatx4 acc[4][4] = {};

  for (int kt = 0; kt < K; kt += 64) {
#pragma unroll
    for (int i = 0; i < 4; ++i) {
      int rbase = w32 + i * 8;
      async16(A + (size_t)(bm + rbase + srow) * K + kt + scol, &As[rbase * 64]);
      async16(WT + (size_t)(bn + rbase + srow) * K + kt + scol, &Bs[rbase * 64]);
    }
    __syncthreads();
#pragma unroll
    for (int ks = 0; ks < 2; ++ks) {
      short8 af[4], bf[4];
#pragma unroll
      for (int mi = 0; mi < 4; ++mi)
        af[mi] = *(const short8*)&As[(wm + mi * 16 + lm) * 64 + ks * 32 + quad * 8];
#pragma unroll
      for (int ni = 0; ni < 4; ++ni)
        bf[ni] = *(const short8*)&Bs[(wn + ni * 16 + lm) * 64 + ks * 32 + quad * 8];
#pragma unroll
      for (int mi = 0; mi < 4; ++mi)
#pragma unroll
        for (int ni = 0; ni < 4; ++ni)
          acc[mi][ni] = __builtin_amdgcn_mfma_f32_16x16x32_bf16(
              af[mi], bf[ni], acc[mi][ni], 0, 0, 0);
    }
    __syncthreads();
  }
#pragma unroll
  for (int ni = 0; ni < 4; ++ni) {
    int col = bn + wn + ni * 16 + lm;
    float bv = f32 ? ((const float*)bias)[col] : b2f(((const unsigned short*)bias)[col]);
#pragma unroll
    for (int mi = 0; mi < 4; ++mi) {
#pragma unroll
      for (int r = 0; r < 4; ++r) {
        int row = bm + wm + mi * 16 + quad * 4 + r;
        float v = acc[mi][ni][r] + bv;
        if (act == 1) v = silu_f(v);
        size_t idx = (size_t)row * Nc + col;
        if (c_ext && f32) ((float*)C)[idx] = v;
        else ((unsigned short*)C)[idx] = f2b(v);
      }
    }
  }
}

// ---------------- kv accumulation: kvT[b,h][e][d] += sum_n elu(K)[n,d] * V[n,e] ----------------
__global__ __launch_bounds__(256) void kv_accum(
    const unsigned short* __restrict__ QK,
    const unsigned short* __restrict__ V,
    float* __restrict__ kvT, int chunk) {
  const int bh = blockIdx.x;
  const int sp = blockIdx.y;
  const int b = bh >> 4, h = bh & 15;
  __shared__ __align__(16) unsigned short Kt[128][72];
  __shared__ __align__(16) unsigned short Vt[128][72];
  const int t = threadIdx.x;
  const int lane = t & 63, wave = t >> 6;
  const int lm = lane & 15, quad = lane >> 4;
  const int wm = (wave >> 1) * 64, wn = (wave & 1) * 64;
  floatx4 acc[4][4] = {};
  const size_t base = (size_t)b * 4096 * 2048 + (size_t)h * 128;
  const int nl = t & 63;
  const int dg0 = t >> 6;
  for (int n0 = sp * chunk; n0 < (sp + 1) * chunk; n0 += 64) {
#pragma unroll
    for (int i = 0; i < 4; ++i) {
      int dg = dg0 + 4 * i;
      union { uint4 u; unsigned short s[8]; } vk, vv;
      vk.u = *(const uint4*)(QK + base + (size_t)(n0 + nl) * 2048 + dg * 8);
      vv.u = *(const uint4*)(V + base + (size_t)(n0 + nl) * 2048 + dg * 8);
#pragma unroll
      for (int j = 0; j < 8; ++j) {
        Kt[dg * 8 + j][nl] = f2b(elu_f(b2f(vk.s[j])));
        Vt[dg * 8 + j][nl] = vv.s[j];
      }
    }
    __syncthreads();
#pragma unroll
    for (int ks = 0; ks < 2; ++ks) {
      short8 af[4], bf[4];
#pragma unroll
      for (int mi = 0; mi < 4; ++mi)
        af[mi] = *(const short8*)&Kt[wm + mi * 16 + lm][ks * 32 + quad * 8];
#pragma unroll
      for (int ni = 0; ni < 4; ++ni)
        bf[ni] = *(const short8*)&Vt[wn + ni * 16 + lm][ks * 32 + quad * 8];
#pragma unroll
      for (int mi = 0; mi < 4; ++mi)
#pragma unroll
        for (int ni = 0; ni < 4; ++ni)
          acc[mi][ni] = __builtin_amdgcn_mfma_f32_16x16x32_bf16(
              af[mi], bf[ni], acc[mi][ni], 0, 0, 0);
    }
    __syncthreads();
  }
  float* dst = kvT + (size_t)bh * 128 * 128;
#pragma unroll
  for (int mi = 0; mi < 4; ++mi)
#pragma unroll
    for (int ni = 0; ni < 4; ++ni)
#pragma unroll
      for (int r = 0; r < 4; ++r) {
        int d = wm + mi * 16 + quad * 4 + r;
        int e = wn + ni * 16 + lm;
        atomicAdd(&dst[e * 128 + d], acc[mi][ni][r]);
      }
}

// ---------------- attention out: O[n, h*128+e] = sum_d elu(Q)[n,d] * kv[d,e] ----------------
__global__ __launch_bounds__(256) void attn_out(
    const unsigned short* __restrict__ QK,
    const float* __restrict__ kvT,
    unsigned short* __restrict__ O) {
  const int h = blockIdx.x;
  const int bm = blockIdx.y * 128;
  const int b = bm >> 12;
  const int bh = b * 16 + h;
  __shared__ __align__(16) unsigned short As[128][136];
  __shared__ __align__(16) unsigned short Bs[128][136];
  const int t = threadIdx.x;
  const int lane = t & 63, wave = t >> 6;
  const int lm = lane & 15, quad = lane >> 4;
  const int wm = (wave >> 1) * 64, wn = (wave & 1) * 64;
  {
    const int r0 = t >> 4;
    const int g = t & 15;
#pragma unroll
    for (int i = 0; i < 8; ++i) {
      int r = r0 + 16 * i;
      union { uint4 u; unsigned short s[8]; } vq, w;
      vq.u = *(const uint4*)(QK + (size_t)(bm + r) * 2048 + h * 128 + g * 8);
#pragma unroll
      for (int j = 0; j < 8; ++j) w.s[j] = f2b(elu_f(b2f(vq.s[j])));
      *(uint4*)&As[r][g * 8] = w.u;
    }
    const int e0 = t >> 5;
    const int gg = t & 31;
    const float* kvp = kvT + (size_t)bh * 16384;
#pragma unroll
    for (int i = 0; i < 16; ++i) {
      int e = e0 + 8 * i;
      float4 f = *(const float4*)(kvp + e * 128 + gg * 4);
      unsigned short o4[4] = {f2b(f.x), f2b(f.y), f2b(f.z), f2b(f.w)};
      *(uint2*)&Bs[e][gg * 4] = *(uint2*)o4;
    }
  }
  __syncthreads();
  floatx4 acc[4][4] = {};
#pragma unroll
  for (int ks = 0; ks < 4; ++ks) {
    short8 af[4], bf[4];
#pragma unroll
    for (int mi = 0; mi < 4; ++mi)
      af[mi] = *(const short8*)&As[wm + mi * 16 + lm][ks * 32 + quad * 8];
#pragma unroll
    for (int ni = 0; ni < 4; ++ni)
      bf[ni] = *(const short8*)&Bs[wn + ni * 16 + lm][ks * 32 + quad * 8];
#pragma unroll
    for (int mi = 0; mi < 4; ++mi)
#pragma unroll
      for (int ni = 0; ni < 4; ++ni)
        acc[mi][ni] = __builtin_amdgcn_mfma_f32_16x16x32_bf16(
            af[mi], bf[ni], acc[mi][ni], 0, 0, 0);
  }
#pragma unroll
  for (int mi = 0; mi < 4; ++mi)
#pragma unroll
    for (int ni = 0; ni < 4; ++ni)
#pragma unroll
      for (int r = 0; r < 4; ++r) {
        int row = bm + wm + mi * 16 + quad * 4 + r;
        int e = wn + ni * 16 + lm;
        O[(size_t)row * 2048 + h * 128 + e] = f2b(acc[mi][ni][r]);
      }
}

// ---------------- layernorm(O) * U -> T ----------------
__global__ __launch_bounds__(256) void ln_mul(
    const unsigned short* __restrict__ O,
    const unsigned short* __restrict__ U,
    const void* __restrict__ g,
    const void* __restrict__ bb,
    unsigned short* __restrict__ T, const int* __restrict__ flag) {
  const bool f32 = is_f32(flag);
  const int row = blockIdx.x;
  const int t = threadIdx.x;
  const unsigned short* o = O + (size_t)row * 2048;
  float vals[8];
  float s = 0.f, s2 = 0.f;
#pragma unroll
  for (int i = 0; i < 8; ++i) {
    float f = b2f(o[t + 256 * i]);
    vals[i] = f;
    s += f;
    s2 += f * f;
  }
#pragma unroll
  for (int off = 32; off > 0; off >>= 1) {
    s += __shfl_down(s, off, 64);
    s2 += __shfl_down(s2, off, 64);
  }
  __shared__ float ps[4], ps2[4];
  int lane = t & 63, wave = t >> 6;
  if (lane == 0) { ps[wave] = s; ps2[wave] = s2; }
  __syncthreads();
  float S = ps[0] + ps[1] + ps[2] + ps[3];
  float S2 = ps2[0] + ps2[1] + ps2[2] + ps2[3];
  float mu = S * (1.f / 2048.f);
  float var = S2 * (1.f / 2048.f) - mu * mu;
  float rs = rsqrtf(var + 1e-5f);
#pragma unroll
  for (int i = 0; i < 8; ++i) {
    int c = t + 256 * i;
    float gv = f32 ? ((const float*)g)[c] : b2f(((const unsigned short*)g)[c]);
    float bv = f32 ? ((const float*)bb)[c] : b2f(((const unsigned short*)bb)[c]);
    float nv = (vals[i] - mu) * rs * gv + bv;
    float uu = b2f(U[(size_t)row * 2048 + c]);
    T[(size_t)row * 2048 + c] = f2b(nv * uu);
  }
}

extern "C" void kernel_launch(void* const* d_in, const int* in_sizes, int n_in,
                              void* d_out, int out_size, void* d_ws, size_t ws_size,
                              hipStream_t stream) {
  const void* x   = d_in[0];
  const void* Wqk = d_in[1];
  const void* bqk = d_in[2];
  const void* Wv  = d_in[3];
  const void* bv  = d_in[4];
  const void* Wu  = d_in[5];
  const void* bu  = d_in[6];
  const void* Wo  = d_in[7];
  const void* bo  = d_in[8];
  const void* lng = d_in[9];
  const void* lnb = d_in[10];

  char* ws = (char*)d_ws;
  const size_t MB = 1024 * 1024;
  int* flag = (int*)ws;                                   // [0, 1MB)
  unsigned short* WT   = (unsigned short*)(ws + 1 * MB);  // 8 MiB (reused 4x)
  unsigned short* buf0 = (unsigned short*)(ws + 16 * MB); // 64 MiB: QK -> U
  unsigned short* buf1 = (unsigned short*)(ws + 80 * MB); // 64 MiB: V -> O -> T
  float* kvT = (float*)(ws + 144 * MB);                   // 4 MiB
  unsigned short* xb = (unsigned short*)(ws + 148 * MB);  // 64 MiB, touched ONLY on f32 path

  dim3 tb(256);
  hipMemsetAsync(flag, 0, 4096, stream);
  hipMemsetAsync(kvT, 0, (size_t)64 * 128 * 128 * 4, stream);
  detect_dtype<<<1, tb, 0, stream>>>((const unsigned int*)x, flag);
  convert_x<<<16384, tb, 0, stream>>>(x, xb, flag);

  const unsigned short* xs = (const unsigned short*)x;
  // QK = x @ Wqk + bqk
  transpose2048<<<dim3(64, 64), tb, 0, stream>>>(Wqk, WT, flag);
  gemm_bias_act<<<dim3(16, 128), tb, 0, stream>>>(xs, xb, 1, WT, bqk, buf0, 0, 2048, 2048, 0, flag);
  // V = silu(x @ Wv + bv)
  transpose2048<<<dim3(64, 64), tb, 0, stream>>>(Wv, WT, flag);
  gemm_bias_act<<<dim3(16, 128), tb, 0, stream>>>(xs, xb, 1, WT, bv, buf1, 0, 2048, 2048, 1, flag);
  // kv = elu(K)^T V
  kv_accum<<<dim3(64, 8), tb, 0, stream>>>(buf0, buf1, kvT, 512);
  // O = elu(Q) @ kv  (overwrites V buffer)
  attn_out<<<dim3(16, 128), tb, 0, stream>>>(buf0, kvT, buf1);
  // U = silu(x @ Wu + bu)  (overwrites QK buffer)
  transpose2048<<<dim3(64, 64), tb, 0, stream>>>(Wu, WT, flag);
  gemm_bias_act<<<dim3(16, 128), tb, 0, stream>>>(xs, xb, 1, WT, bu, buf0, 0, 2048, 2048, 1, flag);
  // T = layernorm(O) * U  (in place over O)
  ln_mul<<<16384, tb, 0, stream>>>(buf1, buf0, lng, lnb, buf1, flag);
  // out = T @ Wo + bo
  transpose2048<<<dim3(64, 64), tb, 0, stream>>>(Wo, WT, flag);
  gemm_bias_act<<<dim3(16, 128), tb, 0, stream>>>(buf1, buf1, 0, WT, bo, d_out, 1, 2048, 2048, 0, flag);
}